// Round 1
// baseline (1077.129 us; speedup 1.0000x reference)
//
#include <hip/hip_runtime.h>

#define L 512
#define HALF 256
#define NSEQ 4096            // B*D = 32*128
#define FIELD 2097152        // 32*512*128

// ---------------------------------------------------------------------------
// In-LDS Stockham radix-2 FFT, 512 points, 256 threads (one butterfly each).
// Input in (aR,aI); output lands in (bR,bI) (9 stages, odd -> ends in b).
// sgn = +1.0f : forward (twiddle table holds e^{-2*pi*i*n/512})
// sgn = -1.0f : inverse (conjugate twiddles; caller applies 1/N scale)
// Leading __syncthreads covers caller's writes into aR/aI and protects bR/bI
// from being overwritten while another thread still reads a previous result.
// ---------------------------------------------------------------------------
__device__ __forceinline__ void fft512(float* aR, float* aI, float* bR, float* bI,
                                       const float* __restrict__ twr,
                                       const float* __restrict__ twi,
                                       int tid, float sgn) {
  __syncthreads();
  float* sR = aR; float* sI = aI; float* dR = bR; float* dI = bI;
#pragma unroll
  for (int s = 0; s < 9; ++s) {
    const int Ns = 1 << s;
    const int jm = tid & (Ns - 1);
    const int ti = jm << (8 - s);          // jm * (256/Ns)
    const float c  = twr[ti];
    const float sn = twi[ti] * sgn;
    const float v0r = sR[tid],        v0i = sI[tid];
    const float v1r = sR[tid + HALF], v1i = sI[tid + HALF];
    const float t1r = v1r * c - v1i * sn;
    const float t1i = v1r * sn + v1i * c;
    const int idxD = ((tid >> s) << (s + 1)) | jm;
    dR[idxD]      = v0r + t1r;  dI[idxD]      = v0i + t1i;
    dR[idxD + Ns] = v0r - t1r;  dI[idxD + Ns] = v0i - t1i;
    __syncthreads();
    float* t;
    t = sR; sR = dR; dR = t;
    t = sI; sI = dI; dI = t;
  }
}

// Mode update in unshifted frequency domain:
//   Traw(m) = (X(m) - Uother(m) + 0.5*lam[m^256]) / (1 + 2*ALPHA*(f(m)-om)^2)
//   Uk(m)   = (Traw(m) + conj(Traw((512-m)&511))) / 2     (Hermitian part)
__device__ __forceinline__ void mode_update(const float* __restrict__ Xr,
                                            const float* __restrict__ Xi,
                                            const float* Uor, const float* Uoi,
                                            float* Ukr, float* Uki,
                                            const float* lam,
                                            float* Ar, float* Ai,
                                            int tid, float om) {
#pragma unroll
  for (int mm = 0; mm < 2; ++mm) {
    const int m = tid + mm * HALF;
    const float f = (float)(m - ((m >> 8) << 9)) * (1.0f / 512.0f);
    const float df = f - om;
    const float den = __builtin_amdgcn_rcpf(fmaf(1600.0f * df, df, 1.0f));
    Ar[m] = (Xr[m] - Uor[m] + 0.5f * lam[m ^ HALF]) * den;
    Ai[m] = (Xi[m] - Uoi[m]) * den;
  }
  __syncthreads();
#pragma unroll
  for (int mm = 0; mm < 2; ++mm) {
    const int m = tid + mm * HALF;
    const int p = (L - m) & (L - 1);
    Ukr[m] = 0.5f * (Ar[m] + Ar[p]);
    Uki[m] = 0.5f * (Ai[m] - Ai[p]);
  }
  __syncthreads();
}

// One block per (b,d) sequence; all state in LDS; 50 iterations in-kernel.
__global__ __launch_bounds__(256) void vmd_kernel(const float* __restrict__ x,
                                                  float* __restrict__ out) {
  __shared__ float Xr[L], Xi[L];
  __shared__ float U0r[L], U0i[L], U1r[L], U1i[L];
  __shared__ float lam[L], xin[L];
  __shared__ float Ar[L], Ai[L], Br[L], Bi[L];
  __shared__ float twr[HALF], twi[HALF];
  __shared__ float red[16];
  __shared__ float omg[2];

  const int tid = threadIdx.x;
  // XCD swizzle: blocks with consecutive work index w (consecutive d) land on
  // the same XCD so stride-512B global accesses share L2 lines.
  const int w = ((blockIdx.x & 7) << 9) + (blockIdx.x >> 3);
  const int b = w >> 7;
  const int d = w & 127;
  const int xbase = (b << 16) + d;     // element (b, m, d) at xbase + m*128

  if (tid < HALF) {
    float s, c;
    sincosf((float)tid * 0.0122718463030851303f, &s, &c);  // 2*pi*n/512
    twr[tid] = c;
    twi[tid] = -s;
  }
#pragma unroll
  for (int mm = 0; mm < 2; ++mm) {
    const int m = tid + mm * HALF;
    const float xv = x[xbase + (m << 7)];
    xin[m] = xv;
    Ar[m] = xv; Ai[m] = 0.0f;
    U0r[m] = 0.0f; U0i[m] = 0.0f; U1r[m] = 0.0f; U1i[m] = 0.0f;
    lam[m] = 0.0f;
  }
  fft512(Ar, Ai, Br, Bi, twr, twi, tid, 1.0f);   // X = fft(x), unshifted order
#pragma unroll
  for (int mm = 0; mm < 2; ++mm) {
    const int m = tid + mm * HALF;
    Xr[m] = Br[m]; Xi[m] = Bi[m];
  }
  __syncthreads();

  float om0 = 0.0f, om1 = 0.0f;

#pragma unroll 1
  for (int it = 0; it < 50; ++it) {
    mode_update(Xr, Xi, U1r, U1i, U0r, U0i, lam, Ar, Ai, tid, om0);
    mode_update(Xr, Xi, U0r, U0i, U1r, U1i, lam, Ar, Ai, tid, om1);

    // omega update: positive freqs are m in [0,256) = tid
    {
      float p0 = U0r[tid] * U0r[tid] + U0i[tid] * U0i[tid];
      float p1 = U1r[tid] * U1r[tid] + U1i[tid] * U1i[tid];
      const float f = (float)tid * (1.0f / 512.0f);
      float n0 = f * p0, n1 = f * p1;
#pragma unroll
      for (int off = 32; off >= 1; off >>= 1) {
        n0 += __shfl_down(n0, off);
        p0 += __shfl_down(p0, off);
        n1 += __shfl_down(n1, off);
        p1 += __shfl_down(p1, off);
      }
      const int wv = tid >> 6;
      if ((tid & 63) == 0) {
        red[wv * 4 + 0] = n0; red[wv * 4 + 1] = p0;
        red[wv * 4 + 2] = n1; red[wv * 4 + 3] = p1;
      }
      __syncthreads();
      if (tid == 0) {
        const float a0 = red[0] + red[4] + red[8]  + red[12];
        const float b0 = red[1] + red[5] + red[9]  + red[13];
        const float a1 = red[2] + red[6] + red[10] + red[14];
        const float b1 = red[3] + red[7] + red[11] + red[15];
        omg[0] = a0 / (b0 + 1e-7f);
        omg[1] = a1 / (b1 + 1e-7f);
      }
      __syncthreads();
      om0 = omg[0]; om1 = omg[1];
    }

    // lam update: sum_u = ifft(U0+U1) (Hermitian -> real)
#pragma unroll
    for (int mm = 0; mm < 2; ++mm) {
      const int m = tid + mm * HALF;
      Ar[m] = U0r[m] + U1r[m];
      Ai[m] = U0i[m] + U1i[m];
    }
    fft512(Ar, Ai, Br, Bi, twr, twi, tid, -1.0f);
#pragma unroll
    for (int mm = 0; mm < 2; ++mm) {
      const int m = tid + mm * HALF;
      lam[m] += 0.001f * (xin[m] - Br[m] * (1.0f / 512.0f));
    }
    __syncthreads();
  }

  // Final time-domain modes; write u0 -> period region, u1 -> res region.
#pragma unroll
  for (int mm = 0; mm < 2; ++mm) {
    const int m = tid + mm * HALF;
    Ar[m] = U0r[m]; Ai[m] = U0i[m];
  }
  fft512(Ar, Ai, Br, Bi, twr, twi, tid, -1.0f);
#pragma unroll
  for (int mm = 0; mm < 2; ++mm) {
    const int m = tid + mm * HALF;
    out[FIELD + xbase + (m << 7)] = Br[m] * (1.0f / 512.0f);
  }
#pragma unroll
  for (int mm = 0; mm < 2; ++mm) {
    const int m = tid + mm * HALF;
    Ar[m] = U1r[m]; Ai[m] = U1i[m];
  }
  fft512(Ar, Ai, Br, Bi, twr, twi, tid, -1.0f);
#pragma unroll
  for (int mm = 0; mm < 2; ++mm) {
    const int m = tid + mm * HALF;
    out[2 * FIELD + xbase + (m << 7)] = Br[m] * (1.0f / 512.0f);
  }
  // Stage omegas in the (to-be-zeroed) trend region: om0 at [w], om1 at [4096+w].
  if (tid == 0) {
    out[w] = om0;
    out[NSEQ + w] = om1;
  }
}

// Reduce omega over D per batch; swap flag at out[8192 + b].
// argsort ascending, stable: swap iff mean(om0) > mean(om1).
__global__ __launch_bounds__(128) void order_kernel(float* __restrict__ out) {
  const int bb = blockIdx.x;
  const int dd = threadIdx.x;
  float o0 = out[bb * 128 + dd];
  float o1 = out[NSEQ + bb * 128 + dd];
#pragma unroll
  for (int off = 32; off >= 1; off >>= 1) {
    o0 += __shfl_down(o0, off);
    o1 += __shfl_down(o1, off);
  }
  __shared__ float s0[2], s1[2];
  const int wv = dd >> 6;
  if ((dd & 63) == 0) { s0[wv] = o0; s1[wv] = o1; }
  __syncthreads();
  if (dd == 0) {
    const float a = s0[0] + s0[1];
    const float c = s1[0] + s1[1];
    out[2 * NSEQ + bb] = (a > c) ? 1.0f : 0.0f;
  }
}

// Conditionally swap period/res per batch.
__global__ __launch_bounds__(256) void swap_kernel(float* __restrict__ out) {
  const int idx = blockIdx.x * 256 + threadIdx.x;   // 0..FIELD-1
  const int bb = idx >> 16;                          // 512*128 elems per batch
  const float flag = out[2 * NSEQ + bb];
  if (flag > 0.5f) {
    const float p = out[FIELD + idx];
    const float r = out[2 * FIELD + idx];
    out[FIELD + idx] = r;
    out[2 * FIELD + idx] = p;
  }
}

extern "C" void kernel_launch(void* const* d_in, const int* in_sizes, int n_in,
                              void* d_out, int out_size, void* d_ws, size_t ws_size,
                              hipStream_t stream) {
  (void)in_sizes; (void)n_in; (void)d_ws; (void)ws_size; (void)out_size;
  const float* x = (const float*)d_in[0];
  float* out = (float*)d_out;
  vmd_kernel<<<NSEQ, 256, 0, stream>>>(x, out);
  order_kernel<<<32, 128, 0, stream>>>(out);
  swap_kernel<<<FIELD / 256, 256, 0, stream>>>(out);
  // Zero the trend output (also wipes the omega/flag staging).
  hipMemsetAsync(out, 0, (size_t)FIELD * sizeof(float), stream);
}

// Round 2
// 624.866 us; speedup vs baseline: 1.7238x; 1.7238x over previous
//
#include <hip/hip_runtime.h>
#include <math.h>

#define FIELD 2097152   // 32*512*128
#define NSEQ  4096      // 32*128 sequences

// ---------------------------------------------------------------------------
// 8-point FFT over a lane's 8 register slots (natural-order DFT).
// inv=false: Y[b] = sum_a x[a] e^{-2pi i ab/8};  inv=true: conjugate twiddles.
// ---------------------------------------------------------------------------
__device__ __forceinline__ void fft8(float* re, float* im, const bool inv) {
  float y0r = re[0]+re[4], y0i = im[0]+im[4];
  float y1r = re[0]-re[4], y1i = im[0]-im[4];
  float y2r = re[2]+re[6], y2i = im[2]+im[6];
  float y3r = re[2]-re[6], y3i = im[2]-im[6];
  float y4r = re[1]+re[5], y4i = im[1]+im[5];
  float y5r = re[1]-re[5], y5i = im[1]-im[5];
  float y6r = re[3]+re[7], y6i = im[3]+im[7];
  float y7r = re[3]-re[7], y7i = im[3]-im[7];
  // multiply by -i (fwd) / +i (inv)
  float t3r = inv ? -y3i : y3i,  t3i = inv ? y3r : -y3r;
  float t7r = inv ? -y7i : y7i,  t7i = inv ? y7r : -y7r;
  float z0r = y0r+y2r, z0i = y0i+y2i;
  float z2r = y0r-y2r, z2i = y0i-y2i;
  float z1r = y1r+t3r, z1i = y1i+t3i;
  float z3r = y1r-t3r, z3i = y1i-t3i;
  float z4r = y4r+y6r, z4i = y4i+y6i;
  float z6r = y4r-y6r, z6i = y4i-y6i;
  float z5r = y5r+t7r, z5i = y5i+t7i;
  float z7r = y5r-t7r, z7i = y5i-t7i;
  const float R = 0.70710678118654752440f;
  const float s = inv ? R : -R;              // imag of w8^{+-1}
  float a5r = R*z5r - s*z5i, a5i = R*z5i + s*z5r;      // w8^{+-1} * z5
  float a6r = inv ? -z6i : z6i, a6i = inv ? z6r : -z6r; // (-+i) * z6
  float a7r = -R*z7r - s*z7i, a7i = -R*z7i + s*z7r;    // w8^{+-3} * z7
  re[0] = z0r+z4r; im[0] = z0i+z4i;
  re[4] = z0r-z4r; im[4] = z0i-z4i;
  re[1] = z1r+a5r; im[1] = z1i+a5i;
  re[5] = z1r-a5r; im[5] = z1i-a5i;
  re[2] = z2r+a6r; im[2] = z2i+a6i;
  re[6] = z2r-a6r; im[6] = z2i-a6i;
  re[3] = z3r+a7r; im[3] = z3i+a7i;
  re[7] = z3r-a7r; im[7] = z3i-a7i;
}

// ---------------------------------------------------------------------------
// 64-point FFT across the wave's lanes for each of 8 slots.
// fwd: radix-2 DIF, natural lane input -> bit-reversed lane output.
// inv: radix-2 DIT, bit-reversed lane input -> natural lane output (conj tw).
// W[s] = e^{-i pi (lane&(h-1)) / h}, h = 32>>s (shared by both directions).
// ---------------------------------------------------------------------------
__device__ __forceinline__ void fft64_fwd(float* vr, float* vi,
                                          const float* Wr, const float* Wi,
                                          int lane) {
#pragma unroll
  for (int s = 0; s < 6; ++s) {
    const int h = 32 >> s;
    const bool hi = (lane & h) != 0;
    const float sg = hi ? -1.0f : 1.0f;
#pragma unroll
    for (int b = 0; b < 8; ++b) {
      float pr = __shfl_xor(vr[b], h, 64);
      float pi = __shfl_xor(vi[b], h, 64);
      float tr = fmaf(sg, vr[b], pr);
      float ti = fmaf(sg, vi[b], pi);
      float mr = tr * Wr[s] - ti * Wi[s];
      float mi = tr * Wi[s] + ti * Wr[s];
      vr[b] = hi ? mr : tr;
      vi[b] = hi ? mi : ti;
    }
  }
}

__device__ __forceinline__ void fft64_inv(float* vr, float* vi,
                                          const float* Wr, const float* Wi,
                                          int lane) {
#pragma unroll
  for (int s = 5; s >= 0; --s) {           // h = 1,2,4,...,32
    const int h = 32 >> s;
    const bool hi = (lane & h) != 0;
    const float sg = hi ? -1.0f : 1.0f;
#pragma unroll
    for (int b = 0; b < 8; ++b) {
      float pr = __shfl_xor(vr[b], h, 64);
      float pi = __shfl_xor(vi[b], h, 64);
      float qr = hi ? vr[b] : pr;          // operand multiplied by conj(W)
      float qi = hi ? vi[b] : pi;
      float rr = hi ? pr : vr[b];          // operand added
      float ri = hi ? pi : vi[b];
      float tr = fmaf(Wr[s], qr,  Wi[s] * qi);   // Re(conj(W)*q)
      float ti = fmaf(Wr[s], qi, -(Wi[s] * qr)); // Im(conj(W)*q)
      vr[b] = fmaf(sg, tr, rr);
      vi[b] = fmaf(sg, ti, ri);
    }
  }
}

// Full 512 FFT: time layout n=64a+lane (slot a) <-> freq layout m=8*rev6(lane)+b
__device__ __forceinline__ void fft512_fwd(float* vr, float* vi,
                                           const float* twFr, const float* twFi,
                                           const float* Wr, const float* Wi,
                                           int lane) {
  fft8(vr, vi, false);
#pragma unroll
  for (int b = 1; b < 8; ++b) {
    float ar = vr[b], ai = vi[b];
    vr[b] = ar * twFr[b] - ai * twFi[b];
    vi[b] = ar * twFi[b] + ai * twFr[b];
  }
  fft64_fwd(vr, vi, Wr, Wi, lane);
}

__device__ __forceinline__ void fft512_inv(float* vr, float* vi,
                                           const float* twFr, const float* twFi,
                                           const float* Wr, const float* Wi,
                                           int lane) {
  fft64_inv(vr, vi, Wr, Wi, lane);
#pragma unroll
  for (int b = 1; b < 8; ++b) {            // multiply by conj(twF)
    float ar = vr[b], ai = vi[b];
    vr[b] = ar * twFr[b] + ai * twFi[b];
    vi[b] = ai * twFr[b] - ar * twFi[b];
  }
  fft8(vr, vi, true);
}

// Mode update in freq domain + Hermitian projection (all-register, 16 bpermutes)
__device__ __forceinline__ void mode_update(const float* Xr, const float* Xi,
                                            const float* Vr, const float* Vi,
                                            float* Ur, float* Ui,
                                            const float* lamF, float om,
                                            float fbase, int pl0, int plx) {
  float Tr[8], Ti[8];
#pragma unroll
  for (int b = 0; b < 8; ++b) {
    float fb = fbase + (float)b * (1.0f / 512.0f);
    float df = fb - om;
    float den = __builtin_amdgcn_rcpf(fmaf(1600.0f * df, df, 1.0f));
    Tr[b] = (Xr[b] - Vr[b] + 0.5f * lamF[b]) * den;
    Ti[b] = (Xi[b] - Vi[b]) * den;
  }
#pragma unroll
  for (int b = 0; b < 8; ++b) {
    const int pb = (8 - b) & 7;
    const int pl = (b == 0) ? pl0 : plx;
    float sr = __shfl(Tr[pb], pl, 64);
    float si = __shfl(Ti[pb], pl, 64);
    Ur[b] = 0.5f * (Tr[b] + sr);
    Ui[b] = 0.5f * (Ti[b] - si);
  }
}

// One wave per (b,d) sequence. 4 waves/block, no __syncthreads anywhere.
__global__ __launch_bounds__(256, 4) void vmd_kernel(const float* __restrict__ x,
                                                     float* __restrict__ out) {
  __shared__ float ldsLam[4 * 576];   // stride-9 permuted lambda per wave
  __shared__ float ldsXin[4 * 512];   // lane-major x per wave

  const int tid = threadIdx.x;
  const int wv = tid >> 6;
  const int lane = tid & 63;
  const int g = blockIdx.x * 4 + wv;          // sequence id 0..4095
  const int bb = g >> 7;
  const int dd = g & 127;
  const int base = (bb << 16) + dd;           // x[(bb,n,dd)] = base + n*128
  float* lamLds = ldsLam + wv * 576;
  float* xinLds = ldsXin + wv * 512;

  const int rev = (int)(__brev((unsigned)lane) >> 26);   // rev6(lane)
  const int m0 = rev << 3;
  const bool pos = (lane & 1) == 0;                       // m < 256
  const float pm = pos ? 1.0f : 0.0f;
  const float fbase = (float)(m0 - (pos ? 0 : 512)) * (1.0f / 512.0f);
  const int plx = lane ^ 63;                              // Hermitian partner b>0
  const int pl0 = (int)(__brev((unsigned)((64 - rev) & 63)) >> 26); // b==0
  const int h3 = lane >> 3;
  const int rev3h = ((h3 & 1) << 2) | (h3 & 2) | ((h3 >> 2) & 1);
  const int wbase = 9 * (rev3h << 3) + (lane & 7);        // lambda write base (dw)
  // per-slot write offsets: 9*(rev3(a)^1)
  const int caOff[8] = {9, 45, 27, 63, 0, 36, 18, 54};

  // FFT64 lane twiddles: W[s] = e^{-i*pi*(lane&(h-1))/h}, h=32>>s
  float Wr[6], Wi[6];
#pragma unroll
  for (int s = 0; s < 6; ++s) {
    const int h = 32 >> s;
    float th = (float)(lane & (h - 1)) * (3.14159265358979323846f / (float)h);
    float sn, cs;
    sincosf(th, &sn, &cs);
    Wr[s] = cs; Wi[s] = -sn;
  }
  // twF[b] = e^{-2pi i lane*b/512}
  float twFr[8], twFi[8];
  twFr[0] = 1.0f; twFi[0] = 0.0f;
#pragma unroll
  for (int b = 1; b < 8; ++b) {
    float th = (float)(lane * b) * 0.01227184630308513f;  // 2pi/512
    float sn, cs;
    sincosf(th, &sn, &cs);
    twFr[b] = cs; twFi[b] = -sn;
  }

  // Load x (T-layout), stage into LDS, forward FFT -> X (F-layout)
  float Xr[8], Xi[8];
#pragma unroll
  for (int a = 0; a < 8; ++a) {
    float xv = x[base + a * 8192 + lane * 128];
    xinLds[lane * 8 + a] = xv;
    Xr[a] = xv; Xi[a] = 0.0f;
  }
  fft512_fwd(Xr, Xi, twFr, twFi, Wr, Wi, lane);

  float U0r[8], U0i[8], U1r[8], U1i[8], lamW[8], lamF[8];
#pragma unroll
  for (int b = 0; b < 8; ++b) {
    U0r[b] = 0.0f; U0i[b] = 0.0f; U1r[b] = 0.0f; U1i[b] = 0.0f;
    lamW[b] = 0.0f; lamF[b] = 0.0f;
  }
  float om0 = 0.0f, om1 = 0.0f;

#pragma unroll 1
  for (int it = 0; it < 50; ++it) {
    mode_update(Xr, Xi, U1r, U1i, U0r, U0i, lamF, om0, fbase, pl0, plx);
    mode_update(Xr, Xi, U0r, U0i, U1r, U1i, lamF, om1, fbase, pl0, plx);

    // omega update (positive freqs = even lanes)
    float n0 = 0.0f, d0 = 0.0f, n1 = 0.0f, d1 = 0.0f;
#pragma unroll
    for (int b = 0; b < 8; ++b) {
      float f = fbase + (float)b * (1.0f / 512.0f);
      float p0 = U0r[b] * U0r[b] + U0i[b] * U0i[b];
      float p1 = U1r[b] * U1r[b] + U1i[b] * U1i[b];
      n0 = fmaf(f, p0, n0); d0 += p0;
      n1 = fmaf(f, p1, n1); d1 += p1;
    }
    n0 *= pm; d0 *= pm; n1 *= pm; d1 *= pm;
#pragma unroll
    for (int off = 32; off >= 1; off >>= 1) {
      n0 += __shfl_xor(n0, off, 64);
      d0 += __shfl_xor(d0, off, 64);
      n1 += __shfl_xor(n1, off, 64);
      d1 += __shfl_xor(d1, off, 64);
    }
    om0 = n0 / (d0 + 1e-7f);
    om1 = n1 / (d1 + 1e-7f);

    // lambda update: sum_u = ifft(U0+U1); lam += tau*(x - sum_u)
    float Sr[8], Si[8];
#pragma unroll
    for (int b = 0; b < 8; ++b) { Sr[b] = U0r[b] + U1r[b]; Si[b] = U0i[b] + U1i[b]; }
    fft512_inv(Sr, Si, twFr, twFi, Wr, Wi, lane);
#pragma unroll
    for (int a = 0; a < 8; ++a) {
      float xv = xinLds[lane * 8 + a];
      lamW[a] = fmaf(0.001f, xv - Sr[a] * (1.0f / 512.0f), lamW[a]);
    }
    // publish permuted lambda for the freq-side readers (intra-wave only)
#pragma unroll
    for (int a = 0; a < 8; ++a) lamLds[wbase + caOff[a]] = lamW[a];
    asm volatile("s_waitcnt lgkmcnt(0)" ::: "memory");
#pragma unroll
    for (int b = 0; b < 8; ++b) lamF[b] = lamLds[9 * lane + b];
  }

  // Final time-domain modes
  float Sr[8], Si[8];
#pragma unroll
  for (int b = 0; b < 8; ++b) { Sr[b] = U0r[b]; Si[b] = U0i[b]; }
  fft512_inv(Sr, Si, twFr, twFi, Wr, Wi, lane);
#pragma unroll
  for (int a = 0; a < 8; ++a)
    out[FIELD + base + a * 8192 + lane * 128] = Sr[a] * (1.0f / 512.0f);
#pragma unroll
  for (int b = 0; b < 8; ++b) { Sr[b] = U1r[b]; Si[b] = U1i[b]; }
  fft512_inv(Sr, Si, twFr, twFi, Wr, Wi, lane);
#pragma unroll
  for (int a = 0; a < 8; ++a)
    out[2 * FIELD + base + a * 8192 + lane * 128] = Sr[a] * (1.0f / 512.0f);

  if (lane == 0) {
    out[g] = om0;            // staged in trend region (zeroed later)
    out[NSEQ + g] = om1;
  }
}

// Reduce omega over D per batch; swap flag at out[2*NSEQ + b].
__global__ __launch_bounds__(128) void order_kernel(float* __restrict__ out) {
  const int bb = blockIdx.x;
  const int dd = threadIdx.x;
  float o0 = out[bb * 128 + dd];
  float o1 = out[NSEQ + bb * 128 + dd];
#pragma unroll
  for (int off = 32; off >= 1; off >>= 1) {
    o0 += __shfl_down(o0, off);
    o1 += __shfl_down(o1, off);
  }
  __shared__ float s0[2], s1[2];
  const int wv = dd >> 6;
  if ((dd & 63) == 0) { s0[wv] = o0; s1[wv] = o1; }
  __syncthreads();
  if (dd == 0) {
    const float a = s0[0] + s0[1];
    const float c = s1[0] + s1[1];
    out[2 * NSEQ + bb] = (a > c) ? 1.0f : 0.0f;
  }
}

// Conditionally swap period/res per batch.
__global__ __launch_bounds__(256) void swap_kernel(float* __restrict__ out) {
  const int idx = blockIdx.x * 256 + threadIdx.x;
  const int bb = idx >> 16;
  const float flag = out[2 * NSEQ + bb];
  if (flag > 0.5f) {
    const float p = out[FIELD + idx];
    const float r = out[2 * FIELD + idx];
    out[FIELD + idx] = r;
    out[2 * FIELD + idx] = p;
  }
}

extern "C" void kernel_launch(void* const* d_in, const int* in_sizes, int n_in,
                              void* d_out, int out_size, void* d_ws, size_t ws_size,
                              hipStream_t stream) {
  (void)in_sizes; (void)n_in; (void)d_ws; (void)ws_size; (void)out_size;
  const float* x = (const float*)d_in[0];
  float* out = (float*)d_out;
  vmd_kernel<<<NSEQ / 4, 256, 0, stream>>>(x, out);
  order_kernel<<<32, 128, 0, stream>>>(out);
  swap_kernel<<<FIELD / 256, 256, 0, stream>>>(out);
  hipMemsetAsync(out, 0, (size_t)FIELD * sizeof(float), stream);
}